// Round 1
// baseline (98.076 us; speedup 1.0000x reference)
//
#include <hip/hip_runtime.h>

// Inverse 2D Haar: out[2i,2j] etc. are +/- combos of LL,LH,HL,HH at (i,j), *0.25.
// Shapes fixed by reference: B=16, C=64, H=128, W=128 -> out (16,64,256,256), fp32.
//
// One thread handles 2 input columns (a float2 from each subband) and writes
// two float4s (one per output row 2i / 2i+1). Fully coalesced both ways.

__global__ __launch_bounds__(256) void ihaar_kernel(
    const float* __restrict__ LL, const float* __restrict__ LH,
    const float* __restrict__ HL, const float* __restrict__ HH,
    float* __restrict__ out, int nPairs)
{
    int t = blockIdx.x * blockDim.x + threadIdx.x;
    if (t >= nPairs) return;

    // t = ((bc*H + i) * W2 + j2), W2 = W/2 = 64, H = 128
    const int W2_SHIFT = 6;   // W/2 = 64
    const int H_SHIFT  = 7;   // H = 128
    int j2   = t & 63;
    int rest = t >> W2_SHIFT;
    int i    = rest & 127;
    int bc   = rest >> H_SHIFT;

    const float2* ll2 = reinterpret_cast<const float2*>(LL);
    const float2* lh2 = reinterpret_cast<const float2*>(LH);
    const float2* hl2 = reinterpret_cast<const float2*>(HL);
    const float2* hh2 = reinterpret_cast<const float2*>(HH);

    float2 ll = ll2[t];
    float2 lh = lh2[t];
    float2 hl = hl2[t];
    float2 hh = hh2[t];

    // column 0
    float a0 = ll.x + lh.x, b0 = ll.x - lh.x;
    float c0 = hl.x + hh.x, d0 = hl.x - hh.x;
    float tl0 = 0.25f * (a0 + c0), tr0 = 0.25f * (a0 - c0);
    float bl0 = 0.25f * (b0 + d0), br0 = 0.25f * (b0 - d0);
    // column 1
    float a1 = ll.y + lh.y, b1 = ll.y - lh.y;
    float c1 = hl.y + hh.y, d1 = hl.y - hh.y;
    float tl1 = 0.25f * (a1 + c1), tr1 = 0.25f * (a1 - c1);
    float bl1 = 0.25f * (b1 + d1), br1 = 0.25f * (b1 - d1);

    // Output: Hout=256, Wout=256; float4 units -> Wout/4 = 64 per row.
    // row0 = bc*256 + 2i, col-block = j2
    float4* out4 = reinterpret_cast<float4*>(out);
    int row0 = (bc << 8) + (i << 1);          // bc*256 + 2*i
    int o0 = (row0 << 6) + j2;                // row * 64 + j2
    int o1 = o0 + 64;                         // next row

    out4[o0] = make_float4(tl0, tr0, tl1, tr1);
    out4[o1] = make_float4(bl0, br0, bl1, br1);
}

extern "C" void kernel_launch(void* const* d_in, const int* in_sizes, int n_in,
                              void* d_out, int out_size, void* d_ws, size_t ws_size,
                              hipStream_t stream) {
    const float* LL = (const float*)d_in[0];
    const float* LH = (const float*)d_in[1];
    const float* HL = (const float*)d_in[2];
    const float* HH = (const float*)d_in[3];
    float* out = (float*)d_out;

    int n = in_sizes[0];          // 16*64*128*128 = 16,777,216
    int nPairs = n >> 1;          // 8,388,608 float2 units
    int block = 256;
    int grid = (nPairs + block - 1) / block;   // 32768 blocks

    hipLaunchKernelGGL(ihaar_kernel, dim3(grid), dim3(block), 0, stream,
                       LL, LH, HL, HH, out, nPairs);
}